// Round 17
// baseline (2591.855 us; speedup 1.0000x reference)
//
#include <hip/hip_runtime.h>
#include <math.h>

#define NTOK   16384
#define DDIM   256
#define HWD    1024        // H*W per batch image
#define CHW    262144      // 256*1024 floats per batch
#define MARGIN 3.0e-4f     // i8 stat (8+ sigma of est-diff) + ref d-grid + fp16 quant
#define CLIPF  5.5f
#define QS     (127.0f/5.5f)
#define EQS    2080768.0f  // 16384*127
#define SCALE  (5.5f/(127.0f*127.0f*16384.0f))   // sz*se

// ws layout (bytes)
#define WS_TI8   0u          // 4 MB  i8 token images [128 tiles][4 chunks][128 rows][64B swz]
#define WS_CI8   4194304u    // 4 MB  i8 code rows PLAIN [code][256]
#define WS_M1    8388608u    // 8 MB  fp16 min1 per 64-code subtile: [n][256]
#define WS_TR8   16777216u   // 4 MB  i8 token rows PLAIN [n][256]
#define WS_FLG   20971520u   // 16KB per-token clip flags
#define WS_EE    20987904u   // 64KB
#define WS_ZZ    21053440u   // 64KB
#define WS_IDX   21118976u   // 64KB
#define WS_CNT   21184512u   // 64KB
#define WS_LSUM  21250048u   // 16KB per-block loss partials [2048] fp64

typedef __attribute__((ext_vector_type(4)))  int   i32x4;
typedef __attribute__((ext_vector_type(16))) char  c16;
typedef __attribute__((ext_vector_type(4)))  _Float16 h4;
typedef unsigned long long ull;

// accumulate exact integer dot of 16 i8 pairs (packed in 4 ints each)
__device__ __forceinline__ int dot16i8(const i32x4 a, const i32x4 b, int acc) {
#if __has_builtin(__builtin_amdgcn_sdot4)
  acc = __builtin_amdgcn_sdot4(a[0], b[0], acc, false);
  acc = __builtin_amdgcn_sdot4(a[1], b[1], acc, false);
  acc = __builtin_amdgcn_sdot4(a[2], b[2], acc, false);
  acc = __builtin_amdgcn_sdot4(a[3], b[3], acc, false);
#else
  #pragma unroll
  for (int i = 0; i < 4; ++i)
    #pragma unroll
    for (int j = 0; j < 4; ++j)
      acc += ((a[i] << (24 - 8 * j)) >> 24) * ((b[i] << (24 - 8 * j)) >> 24);
#endif
  return acc;
}

// ---------------- fused prep: blocks 0..255 tokens, 256..511 codes (R15) ----------------
__global__ __launch_bounds__(256) void k_prep(const float* __restrict__ z,
                                              const float* __restrict__ emb,
                                              char* __restrict__ Ti8,
                                              char* __restrict__ Ci8,
                                              char* __restrict__ Tr8,
                                              float* __restrict__ zz,
                                              float* __restrict__ ee,
                                              float* __restrict__ zt,
                                              unsigned char* __restrict__ flags) {
  const int bid = blockIdx.x;
  const int tid = threadIdx.x;
  const int t64 = tid & 63, chunk = tid >> 6;
  if (bid < 256) {                      // ---- token role
    __shared__ double part[4][64];
    __shared__ int   fpart[4][64];
    const int n = bid * 64 + t64;
    const int b = n >> 10, hw = n & 1023;
    const float* zp = z + (size_t)b * CHW + hw;
    float tmp[64];
    double s = 0.0;
    int clip = 0;
    #pragma unroll
    for (int j = 0; j < 64; ++j) {      // coalesced across t64 for each j
      const float f = zp[(size_t)(chunk * 64 + j) * HWD];
      tmp[j] = f;
      s += (double)f * (double)f;
      clip |= (fabsf(f) > CLIPF) ? 1 : 0;
    }
    c16 q[4];
    #pragma unroll
    for (int sl = 0; sl < 4; ++sl)
      #pragma unroll
      for (int j = 0; j < 16; ++j)
        q[sl][j] = (char)(int)rintf(fminf(fmaxf(tmp[sl * 16 + j], -CLIPF), CLIPF) * QS);
    const int rl = n & 127, tile = n >> 7;
    char* dst = Ti8 + (size_t)tile * 32768 + chunk * 8192 + rl * 64;
    const int sw = ((rl >> 1) & 3) << 4;
    #pragma unroll
    for (int sl = 0; sl < 4; ++sl) *(c16*)(dst + ((sl * 16) ^ sw)) = q[sl];
    char* dst2 = Tr8 + (size_t)n * 256 + chunk * 64;   // plain token row
    #pragma unroll
    for (int sl = 0; sl < 4; ++sl) *(c16*)(dst2 + sl * 16) = q[sl];
    float* ztp = zt + (size_t)n * 256 + chunk * 64;
    #pragma unroll
    for (int j4 = 0; j4 < 16; ++j4) *(float4*)(ztp + j4 * 4) = *(float4*)&tmp[j4 * 4];
    part[chunk][t64] = s;
    fpart[chunk][t64] = clip;
    __syncthreads();
    if (tid < 64) {
      zz[n] = (float)(part[0][t64] + part[1][t64] + part[2][t64] + part[3][t64]);
      flags[n] = (unsigned char)(fpart[0][t64] | fpart[1][t64] | fpart[2][t64] | fpart[3][t64]);
    }
  } else {                              // ---- code role (coalesced via LDS transpose)
    __shared__ float rows[64][257];     // +1 pad
    __shared__ double part2[4][64];
    const int k0 = (bid - 256) * 64;
    for (int i = tid; i < 16384; i += 256)
      rows[i >> 8][i & 255] = emb[(size_t)k0 * DDIM + i];
    __syncthreads();
    const int code = k0 + t64;
    double s = 0.0;
    c16 q[4];
    #pragma unroll
    for (int sl = 0; sl < 4; ++sl)
      #pragma unroll
      for (int j = 0; j < 16; ++j) {
        const float f = rows[t64][chunk * 64 + sl * 16 + j];
        q[sl][j] = (char)(int)rintf(f * EQS);   // range-safe (|e|<=1/16384 -> |q|<=127)
        s += (double)f * (double)f;
      }
    char* dst = Ci8 + (size_t)code * 256 + chunk * 64;   // PLAIN layout
    #pragma unroll
    for (int sl = 0; sl < 4; ++sl) *(c16*)(dst + sl * 16) = q[sl];
    part2[chunk][t64] = s;
    __syncthreads();
    if (tid < 64)
      ee[code] = (float)(part2[0][t64] + part2[1][t64] + part2[2][t64] + part2[3][t64]);
  }
}

// ---------------- phase-1: i8 GEMM (R13 geometry) with MAX-ONLY epilogue (R15) ----------------
__global__ __launch_bounds__(256) void k_mdist(
    const char* __restrict__ tokimg, const char* __restrict__ codrows,
    _Float16* __restrict__ M1) {
  __shared__ __attribute__((aligned(16))) char ldsB[65536];   // 2 x 32KB token tiles
  __shared__ _Float16 m1l[2][256];
  const int raw = blockIdx.x;
  const int p = raw & 7;                        // XCD
  const int ctile = p * 16 + ((raw >> 3) & 15); // 0..127
  const int tgrp = raw >> 7;                    // 0..15 (8 ttiles each)
  const int tid = threadIdx.x;
  const int w = tid >> 6, lane = tid & 63;
  const int wr = w >> 1, wc = w & 1;            // code-half, token-half
  const int fr = lane & 15, fq = lane >> 4;

  // A-frags: 64 codes x K=256 in VGPRs, loaded once from plain rows
  i32x4 afr[4][4];                              // [m][kc]
  {
    const char* ab = codrows + (size_t)(ctile * 128 + wr * 64 + fr) * 256 + fq * 16;
    #pragma unroll
    for (int m = 0; m < 4; ++m)
      #pragma unroll
      for (int kc = 0; kc < 4; ++kc)
        afr[m][kc] = *(const i32x4*)(ab + m * 16 * 256 + kc * 64);
  }

  int boff[4][4];                               // [n][kc] LDS offsets (swizzled image)
  #pragma unroll
  for (int n = 0; n < 4; ++n)
    #pragma unroll
    for (int kc = 0; kc < 4; ++kc) {
      const int t = wc * 64 + n * 16 + fr;
      boff[n][kc] = kc * 8192 + t * 64 + ((fq * 16) ^ (((t >> 1) & 3) << 4));
    }

  #define STAGEB(buf, tt)                                                             \
    {                                                                                 \
      const char* src = tokimg + (size_t)(tt) * 32768;                                \
      char* dstb = ldsB + (buf) * 32768;                                              \
      _Pragma("unroll")                                                               \
      for (int r = 0; r < 8; ++r) {                                                   \
        const int u = r * 256 + tid;                                                  \
        __builtin_amdgcn_global_load_lds(                                             \
            (const __attribute__((address_space(1))) void*)(src + u * 16),            \
            (__attribute__((address_space(3))) void*)(dstb + u * 16), 16, 0, 0);      \
      }                                                                               \
    }

  STAGEB(0, tgrp * 8);
  __syncthreads();                              // buf0 ready

  for (int it = 0; it < 8; ++it) {
    const int pb = it & 1;
    const int ttile = tgrp * 8 + it;
    if (it < 7) STAGEB(pb ^ 1, ttile + 1);      // prefetch next B
    const char* bufb = ldsB + pb * 32768;

    i32x4 acc[4][4];
    #pragma unroll
    for (int m = 0; m < 4; ++m)
      #pragma unroll
      for (int n = 0; n < 4; ++n) acc[m][n] = (i32x4)0;

    __builtin_amdgcn_s_setprio(1);
    #pragma unroll
    for (int kc = 0; kc < 4; ++kc) {
      i32x4 b[4];
      #pragma unroll
      for (int n = 0; n < 4; ++n) b[n] = *(const i32x4*)(bufb + boff[n][kc]);
      #pragma unroll
      for (int m = 0; m < 4; ++m)
        #pragma unroll
        for (int n = 0; n < 4; ++n)
          acc[m][n] = __builtin_amdgcn_mfma_i32_16x16x64_i8(afr[m][kc], b[n], acc[m][n], 0, 0, 0);
    }
    __builtin_amdgcn_s_setprio(0);

    // MAX-ONLY epilogue per (token fr+n*16, wr-subtile)
    #pragma unroll
    for (int n = 0; n < 4; ++n) {
      int v = max(max(acc[0][n][0], acc[0][n][1]), max(acc[0][n][2], acc[0][n][3]));
      #pragma unroll
      for (int m = 1; m < 4; ++m)
        v = max(v, max(max(acc[m][n][0], acc[m][n][1]), max(acc[m][n][2], acc[m][n][3])));
      v = max(v, __shfl_xor(v, 16, 64));
      v = max(v, __shfl_xor(v, 32, 64));        // max over 64 codes of wr-subtile
      if (lane < 16)
        m1l[pb][(wc * 64 + n * 16 + fr) * 2 + wr] = (_Float16)(-2.0f * SCALE * (float)v);
    }
    __syncthreads();                    // fences m1l[pb] + drains stage(it+1)
    if (tid < 128) {
      const int tok = ttile * 128 + tid;
      *(unsigned int*)((char*)M1 + (size_t)tok * 512 + ctile * 4) =
          *(const unsigned int*)(&m1l[pb][tid * 2]);
    }
    // no trailing barrier: m1l double-buffered (safe per next iter's barrier ordering)
  }
}

// ---------------- phase-2: wave-per-token; IN-LANE integer expansion + coalesced fp64 argmin ----------------
// grid 2048 x 256 thr = 4 waves; each wave owns 2 tokens. Candidate 64-code subtiles from
// M1; expansion: lane l computes EXACT integer d_est of code sub*64+l via 16 accumulating
// sdot4 chunks against the register-resident token row (NO cross-lane ops). Surviving
// codes (~2-3/token) get the R13-style coalesced fp64 recheck (16 lanes/code).
__global__ __launch_bounds__(256) void k_pick(
    const float* __restrict__ zt, const float* __restrict__ emb,
    const float* __restrict__ zz, const float* __restrict__ ee,
    const _Float16* __restrict__ M1, const char* __restrict__ Tr8,
    const char* __restrict__ Ci8, const unsigned char* __restrict__ flags,
    int* __restrict__ idx, float* __restrict__ out_idxf,
    int* __restrict__ counts, double* __restrict__ lsum) {
  __shared__ float zrow[4][260];        // per-wave z row
  __shared__ int   clist[4][128];       // per-wave candidate codes
  __shared__ int   slist[4][16];        // per-wave candidate subtiles
  __shared__ int   wcnt[4], scnt[4];
  __shared__ double wsum[4];
  const int tid = threadIdx.x;
  const int w = tid >> 6, lane = tid & 63;
  const int g16 = lane >> 4, l16 = lane & 15;
  double dsum = 0.0;
  for (int ni = 0; ni < 2; ++ni) {
    const int n = blockIdx.x * 8 + w * 2 + ni;
    if (lane == 0) { wcnt[w] = 0; scnt[w] = 0; }
    // z row: 64 lanes x float4 (coalesced 1KB)
    *(float4*)&zrow[w][lane * 4] = *(const float4*)(zt + (size_t)n * 256 + lane * 4);
    // token i8 row -> 16 x i32x4 in registers (broadcast loads, L2-hot)
    i32x4 t16[16];
    #pragma unroll
    for (int c = 0; c < 16; ++c)
      t16[c] = *(const i32x4*)(Tr8 + (size_t)n * 256 + c * 16);
    // M1 scan: lane covers subtiles lane*4..+3 (coalesced 8B/lane)
    const h4 mv = *(const h4*)(M1 + (size_t)n * 256 + lane * 4);
    float ta4[4];
    #pragma unroll
    for (int s = 0; s < 4; ++s) ta4[s] = (float)mv[s];
    float mr = fminf(fminf(ta4[0], ta4[1]), fminf(ta4[2], ta4[3]));
    #pragma unroll
    for (int o = 32; o; o >>= 1) mr = fminf(mr, __shfl_xor(mr, o, 64));
    const int ex0 = flags[n];
    const float thr = ex0 ? 3.0e38f : mr + MARGIN;
    if (!ex0) {
      #pragma unroll
      for (int s = 0; s < 4; ++s) {
        if (ta4[s] <= thr) {
          const int pos = atomicAdd(&scnt[w], 1);
          if (pos < 16) slist[w][pos] = lane * 4 + s;
        }
      }
    }
    const int ns = scnt[w];             // same-wave DS order: pushes visible
    int doEx = ex0 || (ns > 16);
    if (!doEx) {
      for (int si = 0; si < ns; ++si) { // in-lane expansion: 64 codes across 64 lanes
        const int k = slist[w][si] * 64 + lane;
        const char* cr = Ci8 + (size_t)k * 256;
        int v = 0;
        #pragma unroll
        for (int c = 0; c < 16; ++c)
          v = dot16i8(t16[c], *(const i32x4*)(cr + c * 16), v);
        const float dest = -2.0f * SCALE * (float)v;   // exact integer -> fp32
        if (dest <= thr) {
          const int pos = atomicAdd(&wcnt[w], 1);
          if (pos < 128) clist[w][pos] = k;
        }
      }
      if (wcnt[w] > 128 || wcnt[w] == 0) doEx = 1;     // overflow/empty safety
    }
    const int cnt = wcnt[w];
    const int nc = doEx ? 16384 : cnt;
    const float zzn = zz[n];
    ull best = ~0ull;
    for (int ci = 0; ci < nc; ci += 4) {          // 4 codes in parallel (16 lanes each)
      int k;
      if (doEx) k = ci + g16;
      else { const int sl = ci + g16; k = clist[w][sl < cnt ? sl : 0]; }  // dup harmless
      const float* erow = emb + (size_t)k * DDIM;
      double s = 0.0;
      #pragma unroll
      for (int qq = 0; qq < 4; ++qq) {
        const float4 ev = *(const float4*)(erow + qq * 64 + l16 * 4);     // coalesced
        const float4 zv = *(const float4*)(&zrow[w][qq * 64 + l16 * 4]);  // broadcast
        s += (double)zv.x * (double)ev.x + (double)zv.y * (double)ev.y
           + (double)zv.z * (double)ev.z + (double)zv.w * (double)ev.w;
      }
      #pragma unroll
      for (int o = 8; o; o >>= 1) s += __shfl_xor(s, o, 16);
      if (l16 == 0) {
        const float mm = (float)s;                   // exact dot -> one fp32 rounding
        const float d = (zzn + ee[k]) - 2.0f * mm;   // replicate ref quantization (d > 0)
        const ull c = ((ull)__float_as_uint(d) << 32) | (unsigned int)k;
        if (c < best) best = c;                      // lexicographic (d, k): first idx wins
      }
    }
    ull b0 = (l16 == 0) ? best : ~0ull;
    {
      const ull o1 = __shfl_xor(b0, 16, 64);
      b0 = o1 < b0 ? o1 : b0;
      const ull o2 = __shfl_xor(b0, 32, 64);
      b0 = o2 < b0 ? o2 : b0;
    }
    if (lane == 0) {
      const int k0 = (int)(b0 & 0xffffffffu);
      idx[n] = k0;
      out_idxf[n] = (float)k0;
      atomicAdd(&counts[k0], 1);
      dsum += (double)__uint_as_float((unsigned int)(b0 >> 32));  // winner d = sum((zq-z)^2)
    }
  }
  if (lane == 0) wsum[w] = dsum;
  __syncthreads();
  if (tid == 0) lsum[blockIdx.x] = wsum[0] + wsum[1] + wsum[2] + wsum[3];
}

// ---------------- scatter z_q: pure gather + coalesced NCHW write (R13) ----------------
__global__ __launch_bounds__(256) void k_scatter(
    const float* __restrict__ emb, const int* __restrict__ idx,
    float* __restrict__ out_zq) {
  __shared__ float et[64][257];   // 64 tokens x 256 dims, pad 257
  __shared__ int sidx[64];
  const int tg = blockIdx.x;      // 256 groups of 64 tokens
  const int n0 = tg * 64;
  const int b = n0 >> 10, hw0 = n0 & 1023;
  const int tid = threadIdx.x;
  if (tid < 64) sidx[tid] = idx[n0 + tid];
  __syncthreads();
  for (int i = tid; i < 16384; i += 256) {      // gather code rows (coalesced along d)
    const int t = i >> 8, d = i & 255;
    et[t][d] = emb[(size_t)sidx[t] * DDIM + d];
  }
  __syncthreads();
  float* ob = out_zq + (size_t)b * CHW + hw0;
  for (int i = tid; i < 16384; i += 256) {      // NCHW order: coalesced zq writes
    const int d = i >> 6, t = i & 63;
    ob[(size_t)d * HWD + t] = et[t][d];         // z_q_st == z_q numerically
  }
}

// ---------------- entropy + loss finals (single block, R13) ----------------
__global__ __launch_bounds__(256) void k_histfinal(const int* __restrict__ counts,
                                                   const double* __restrict__ lsum,
                                                   float* __restrict__ out_loss,
                                                   float* __restrict__ out_perp) {
  __shared__ double w4[4], l4a[4];
  const int tid = threadIdx.x;
  double s = 0.0, l = 0.0;
  for (int i = tid; i < 16384; i += 256) {
    const float em = (float)counts[i] * (1.0f / 16384.0f);
    s += (double)(em * logf(em + 1e-10f));
  }
  for (int i = tid; i < 2048; i += 256) l += lsum[i];
  #pragma unroll
  for (int o = 32; o; o >>= 1) {
    s += __shfl_xor(s, o, 64);
    l += __shfl_xor(l, o, 64);
  }
  const int wid = tid >> 6, lane = tid & 63;
  if (lane == 0) { w4[wid] = s; l4a[wid] = l; }
  __syncthreads();
  if (tid == 0) {
    const double S = w4[0] + w4[1] + w4[2] + w4[3];
    const double L = l4a[0] + l4a[1] + l4a[2] + l4a[3];
    out_loss[0] = (float)(1.25 * L / 4194304.0);  // (1+BETA)*mean
    out_perp[0] = (float)exp(-S);
  }
}

extern "C" void kernel_launch(void* const* d_in, const int* in_sizes, int n_in,
                              void* d_out, int out_size, void* d_ws, size_t ws_size,
                              hipStream_t stream) {
  const float* z   = (const float*)d_in[0];   // [16,256,32,32]
  const float* emb = (const float*)d_in[1];   // [16384,256]
  float* out      = (float*)d_out;
  float* out_zq   = out;                      // 4194304
  float* out_loss = out + 4194304;
  float* out_perp = out + 4194305;
  float* out_idxf = out + 4194306;            // 16384 (idx as float)
  float* zt       = out;                      // [n][d] fp32; dead before k_scatter overwrites

  char* ws = (char*)d_ws;
  char* Ti8 = ws + WS_TI8;
  char* Ci8 = ws + WS_CI8;
  char* Tr8 = ws + WS_TR8;
  _Float16* M1 = (_Float16*)(ws + WS_M1);
  unsigned char* flags = (unsigned char*)(ws + WS_FLG);
  float*  ee      = (float*)(ws + WS_EE);
  float*  zz      = (float*)(ws + WS_ZZ);
  int*    idx     = (int*)  (ws + WS_IDX);
  int*    counts  = (int*)  (ws + WS_CNT);
  double* lsum    = (double*)(ws + WS_LSUM);

  hipMemsetAsync(counts, 0, 65536, stream);

  k_prep <<<512, 256, 0, stream>>>(z, emb, Ti8, Ci8, Tr8, zz, ee, zt, flags);
  k_mdist<<<2048, 256, 0, stream>>>(Ti8, Ci8, M1);
  k_pick <<<2048, 256, 0, stream>>>(zt, emb, zz, ee, M1, Tr8, Ci8, flags,
                                    idx, out_idxf, counts, lsum);
  k_scatter<<<256, 256, 0, stream>>>(emb, idx, out_zq);
  k_histfinal<<<1, 256, 0, stream>>>(counts, lsum, out_loss, out_perp);
}

// Round 18
// 196.876 us; speedup vs baseline: 13.1649x; 13.1649x over previous
//
#include <hip/hip_runtime.h>
#include <math.h>

#define NTOK   16384
#define DDIM   256
#define HWD    1024        // H*W per batch image
#define CHW    262144      // 256*1024 floats per batch
#define MARGIN 3.0e-4f     // i8 stat (8+ sigma of est-diff) + ref d-grid + fp16 quant
#define CLIPF  5.5f
#define QS     (127.0f/5.5f)
#define EQS    2080768.0f  // 16384*127
#define SCALE  (5.5f/(127.0f*127.0f*16384.0f))   // sz*se

// ws layout (bytes)
#define WS_TI8   0u          // 4 MB  i8 token images [128 tiles][4 chunks][128 rows][64B swz]
#define WS_CI8   4194304u    // 4 MB  i8 code rows PLAIN [code][256]
#define WS_M1    8388608u    // 8 MB  fp16 min1: [n][256 subtiles]
#define WS_M2    16777216u   // 8 MB  fp16 min2: [256 subtiles][n]
#define WS_ARG   25165824u   // 4 MB  u8 argmin-in-subtile: [256 subtiles][n]
#define WS_FLG   29360128u   // 16KB per-token clip flags
#define WS_EE    29376512u   // 64KB
#define WS_ZZ    29442048u   // 64KB
#define WS_IDX   29507584u   // 64KB
#define WS_CNT   29573120u   // 64KB
#define WS_LSUM  29638656u   // 16KB per-block loss partials [2048] fp64

typedef __attribute__((ext_vector_type(4)))  int   i32x4;
typedef __attribute__((ext_vector_type(16))) char  c16;
typedef __attribute__((ext_vector_type(4)))  _Float16 h4;

__device__ __forceinline__ void top2m(int& a1, int& a2, const int b1, const int b2) {
  const int mn = min(a1, b1);          // merge (a1,a2) with (b1,b2)
  a1 = max(a1, b1);
  a2 = max(max(a2, b2), mn);           // max3
}

// ---------------- fused prep: blocks 0..255 tokens, 256..511 codes ----------------
__global__ __launch_bounds__(256) void k_prep(const float* __restrict__ z,
                                              const float* __restrict__ emb,
                                              char* __restrict__ Ti8,
                                              char* __restrict__ Ci8,
                                              float* __restrict__ zz,
                                              float* __restrict__ ee,
                                              float* __restrict__ zt,
                                              unsigned char* __restrict__ flags) {
  const int bid = blockIdx.x;
  const int tid = threadIdx.x;
  const int t64 = tid & 63, chunk = tid >> 6;
  if (bid < 256) {                      // ---- token role
    __shared__ double part[4][64];
    __shared__ int   fpart[4][64];
    const int n = bid * 64 + t64;
    const int b = n >> 10, hw = n & 1023;
    const float* zp = z + (size_t)b * CHW + hw;
    float tmp[64];
    double s = 0.0;
    int clip = 0;
    #pragma unroll
    for (int j = 0; j < 64; ++j) {      // coalesced across t64 for each j
      const float f = zp[(size_t)(chunk * 64 + j) * HWD];
      tmp[j] = f;
      s += (double)f * (double)f;
      clip |= (fabsf(f) > CLIPF) ? 1 : 0;
    }
    c16 q[4];
    #pragma unroll
    for (int sl = 0; sl < 4; ++sl)
      #pragma unroll
      for (int j = 0; j < 16; ++j)
        q[sl][j] = (char)(int)rintf(fminf(fmaxf(tmp[sl * 16 + j], -CLIPF), CLIPF) * QS);
    const int rl = n & 127, tile = n >> 7;
    char* dst = Ti8 + (size_t)tile * 32768 + chunk * 8192 + rl * 64;
    const int sw = ((rl >> 1) & 3) << 4;
    #pragma unroll
    for (int sl = 0; sl < 4; ++sl) *(c16*)(dst + ((sl * 16) ^ sw)) = q[sl];
    float* ztp = zt + (size_t)n * 256 + chunk * 64;
    #pragma unroll
    for (int j4 = 0; j4 < 16; ++j4) *(float4*)(ztp + j4 * 4) = *(float4*)&tmp[j4 * 4];
    part[chunk][t64] = s;
    fpart[chunk][t64] = clip;
    __syncthreads();
    if (tid < 64) {
      zz[n] = (float)(part[0][t64] + part[1][t64] + part[2][t64] + part[3][t64]);
      flags[n] = (unsigned char)(fpart[0][t64] | fpart[1][t64] | fpart[2][t64] | fpart[3][t64]);
    }
  } else {                              // ---- code role (coalesced via LDS transpose)
    __shared__ float rows[64][257];     // +1 pad
    __shared__ double part2[4][64];
    const int k0 = (bid - 256) * 64;
    for (int i = tid; i < 16384; i += 256)
      rows[i >> 8][i & 255] = emb[(size_t)k0 * DDIM + i];
    __syncthreads();
    const int code = k0 + t64;
    double s = 0.0;
    c16 q[4];
    #pragma unroll
    for (int sl = 0; sl < 4; ++sl)
      #pragma unroll
      for (int j = 0; j < 16; ++j) {
        const float f = rows[t64][chunk * 64 + sl * 16 + j];
        q[sl][j] = (char)(int)rintf(f * EQS);   // range-safe (|e|<=1/16384 -> |q|<=127)
        s += (double)f * (double)f;
      }
    char* dst = Ci8 + (size_t)code * 256 + chunk * 64;   // PLAIN layout
    #pragma unroll
    for (int sl = 0; sl < 4; ++sl) *(c16*)(dst + sl * 16) = q[sl];
    part2[chunk][t64] = s;
    __syncthreads();
    if (tid < 64)
      ee[code] = (float)(part2[0][t64] + part2[1][t64] + part2[2][t64] + part2[3][t64]);
  }
}

// ---------------- phase-1: i8 GEMM, codes-in-VGPR, 8 token-tiles per block ----------------
// grid 2048 = 8 XCD x 16 ctile-local x 16 ttile-groups; 256 thr = 4 waves (2 code x 2 token).
// Block: ctile (128 codes, A-frags in VGPR) x 8 ttiles of 128 tokens (B dbuf in LDS).
// ONE barrier per iter (out-arrays double-buffered). Branchless packed-key top-2 epilogue.
__global__ __launch_bounds__(256, 1) void k_mdist(
    const char* __restrict__ tokimg, const char* __restrict__ codrows,
    _Float16* __restrict__ M1, _Float16* __restrict__ M2,
    unsigned char* __restrict__ ARG) {
  __shared__ __attribute__((aligned(16))) char ldsB[65536];   // 2 x 32KB token tiles
  __shared__ _Float16 m1l[2][256];
  __shared__ _Float16 m2l[2][256];
  __shared__ unsigned char agl[2][256];
  const int raw = blockIdx.x;
  const int p = raw & 7;                        // XCD
  const int ctile = p * 16 + ((raw >> 3) & 15); // 0..127
  const int tgrp = raw >> 7;                    // 0..15 (8 ttiles each)
  const int tid = threadIdx.x;
  const int w = tid >> 6, lane = tid & 63;
  const int wr = w >> 1, wc = w & 1;            // code-half, token-half
  const int fr = lane & 15, fq = lane >> 4;

  // A-frags: 64 codes x K=256 in VGPRs, loaded once from plain rows
  i32x4 afr[4][4];                              // [m][kc]
  {
    const char* ab = codrows + (size_t)(ctile * 128 + wr * 64 + fr) * 256 + fq * 16;
    #pragma unroll
    for (int m = 0; m < 4; ++m)
      #pragma unroll
      for (int kc = 0; kc < 4; ++kc)
        afr[m][kc] = *(const i32x4*)(ab + m * 16 * 256 + kc * 64);
  }
  // opaque pin: values become asm outputs -> compiler cannot re-load them from memory
  #pragma unroll
  for (int m = 0; m < 4; ++m)
    #pragma unroll
    for (int kc = 0; kc < 4; ++kc)
      asm volatile("" : "+v"(afr[m][kc]));

  int boff[4][4];                               // [n][kc] LDS offsets (swizzled image)
  #pragma unroll
  for (int n = 0; n < 4; ++n)
    #pragma unroll
    for (int kc = 0; kc < 4; ++kc) {
      const int t = wc * 64 + n * 16 + fr;
      boff[n][kc] = kc * 8192 + t * 64 + ((fq * 16) ^ (((t >> 1) & 3) << 4));
    }

  #define STAGEB(buf, tt)                                                             \
    {                                                                                 \
      const char* src = tokimg + (size_t)(tt) * 32768;                                \
      char* dstb = ldsB + (buf) * 32768;                                              \
      _Pragma("unroll")                                                               \
      for (int r = 0; r < 8; ++r) {                                                   \
        const int u = r * 256 + tid;                                                  \
        __builtin_amdgcn_global_load_lds(                                             \
            (const __attribute__((address_space(1))) void*)(src + u * 16),            \
            (__attribute__((address_space(3))) void*)(dstb + u * 16), 16, 0, 0);      \
      }                                                                               \
    }

  STAGEB(0, tgrp * 8);
  __syncthreads();                              // buf0 ready

  const int fq4 = fq * 4;
  for (int it = 0; it < 8; ++it) {
    const int pb = it & 1;
    const int ttile = tgrp * 8 + it;
    if (it < 7) STAGEB(pb ^ 1, ttile + 1);      // prefetch next B
    const char* bufb = ldsB + pb * 32768;

    i32x4 acc[4][4];
    #pragma unroll
    for (int m = 0; m < 4; ++m)
      #pragma unroll
      for (int n = 0; n < 4; ++n) acc[m][n] = (i32x4)0;

    __builtin_amdgcn_s_setprio(1);
    #pragma unroll
    for (int kc = 0; kc < 4; ++kc) {
      i32x4 b[4];
      #pragma unroll
      for (int n = 0; n < 4; ++n) b[n] = *(const i32x4*)(bufb + boff[n][kc]);
      #pragma unroll
      for (int m = 0; m < 4; ++m)
        #pragma unroll
        for (int n = 0; n < 4; ++n)
          acc[m][n] = __builtin_amdgcn_mfma_i32_16x16x64_i8(afr[m][kc], b[n], acc[m][n], 0, 0, 0);
    }
    __builtin_amdgcn_s_setprio(0);

    // branchless packed-key top-2 per (token fr+n*16, wr-subtile)
    #pragma unroll
    for (int n = 0; n < 4; ++n) {
      int p1[8], p2[8];
      #pragma unroll
      for (int m = 0; m < 4; ++m)
        #pragma unroll
        for (int jj = 0; jj < 2; ++jj) {
          const int k0 = (acc[m][n][2 * jj]     << 8) | (m * 16 + fq4 + 2 * jj);
          const int k1 = (acc[m][n][2 * jj + 1] << 8) | (m * 16 + fq4 + 2 * jj + 1);
          p1[m * 2 + jj] = max(k0, k1);
          p2[m * 2 + jj] = min(k0, k1);
        }
      top2m(p1[0], p2[0], p1[1], p2[1]); top2m(p1[2], p2[2], p1[3], p2[3]);
      top2m(p1[4], p2[4], p1[5], p2[5]); top2m(p1[6], p2[6], p1[7], p2[7]);
      top2m(p1[0], p2[0], p1[2], p2[2]); top2m(p1[4], p2[4], p1[6], p2[6]);
      top2m(p1[0], p2[0], p1[4], p2[4]);
      int k1 = p1[0], k2 = p2[0];
      #pragma unroll
      for (int off = 16; off <= 32; off <<= 1) {
        const int o1 = __shfl_xor(k1, off, 64);
        const int o2 = __shfl_xor(k2, off, 64);
        top2m(k1, k2, o1, o2);
      }
      if (lane < 16) {
        const int tl = wc * 64 + n * 16 + fr;
        m1l[pb][tl * 2 + wr] = (_Float16)(-2.0f * SCALE * (float)(k1 >> 8));
        m2l[pb][tl * 2 + wr] = (_Float16)(-2.0f * SCALE * (float)(k2 >> 8));
        agl[pb][tl * 2 + wr] = (unsigned char)(k1 & 255);
      }
    }
    __syncthreads();                    // single barrier: fences m1l[pb] + drains stage(it+1)
    if (tid < 128) {
      const int tok = ttile * 128 + tid;
      *(unsigned int*)((char*)M1 + (size_t)tok * 512 + ctile * 4) =
          *(const unsigned int*)(&m1l[pb][tid * 2]);
      M2[(size_t)(ctile * 2) * NTOK + tok]     = m2l[pb][tid * 2];
      M2[(size_t)(ctile * 2 + 1) * NTOK + tok] = m2l[pb][tid * 2 + 1];
      ARG[(size_t)(ctile * 2) * NTOK + tok]     = agl[pb][tid * 2];
      ARG[(size_t)(ctile * 2 + 1) * NTOK + tok] = agl[pb][tid * 2 + 1];
    }
    // no trailing barrier: out-arrays double-buffered (safe per next iter's barrier)
  }
}

// ---------------- phase-2: barrier-free wave-per-token exact argmin + loss/counts ----------------
__global__ __launch_bounds__(256) void k_pick(
    const float* __restrict__ zt, const float* __restrict__ emb,
    const float* __restrict__ zz, const float* __restrict__ ee,
    const _Float16* __restrict__ M1, const _Float16* __restrict__ M2,
    const unsigned char* __restrict__ ARG, const unsigned char* __restrict__ flags,
    int* __restrict__ idx, float* __restrict__ out_idxf,
    int* __restrict__ counts, double* __restrict__ lsum) {
  __shared__ float zrow[4][260];        // per-wave z row
  __shared__ int   clist[4][576];       // per-wave candidate codes
  __shared__ int   wcnt[4];
  __shared__ double wsum[4];
  const int tid = threadIdx.x;
  const int w = tid >> 6, lane = tid & 63;
  const int g16 = lane >> 4, l16 = lane & 15;
  double dsum = 0.0;
  for (int ni = 0; ni < 2; ++ni) {
    const int n = blockIdx.x * 8 + w * 2 + ni;
    if (lane == 0) wcnt[w] = 0;
    // z row: 64 lanes x float4 (coalesced 1KB)
    *(float4*)&zrow[w][lane * 4] = *(const float4*)(zt + (size_t)n * 256 + lane * 4);
    // M1 scan: lane covers subtiles lane*4..+3 (coalesced 8B/lane)
    const h4 mv = *(const h4*)(M1 + (size_t)n * 256 + lane * 4);
    float ta4[4];
    #pragma unroll
    for (int s = 0; s < 4; ++s) ta4[s] = (float)mv[s];
    float mr = fminf(fminf(ta4[0], ta4[1]), fminf(ta4[2], ta4[3]));
    #pragma unroll
    for (int o = 32; o; o >>= 1) mr = fminf(mr, __shfl_xor(mr, o, 64));
    const int ex0 = flags[n];
    const float thr = ex0 ? 3.0e38f : mr + MARGIN;
    if (!ex0) {
      #pragma unroll
      for (int s = 0; s < 4; ++s) {
        if (ta4[s] <= thr) {
          const int sub = lane * 4 + s;
          const float m2v = (float)M2[(size_t)sub * NTOK + n];
          if (m2v > thr) {              // only the argmin code can be in the window
            const int pos = atomicAdd(&wcnt[w], 1);
            if (pos < 576) clist[w][pos] = sub * 64 + (int)ARG[(size_t)sub * NTOK + n];
          } else {                      // rare: 2+ codes in window -> whole subtile
            const int pos = atomicAdd(&wcnt[w], 64);
            if (pos + 64 <= 576)
              for (int i = 0; i < 64; ++i) clist[w][pos + i] = sub * 64 + i;
          }
        }
      }
    }
    const int cnt = wcnt[w];            // same-wave DS order: all pushes visible
    const int doEx = ex0 || (cnt > 576);
    const int nc = doEx ? 16384 : cnt;
    const float zzn = zz[n];
    unsigned long long best = ~0ull;
    for (int ci = 0; ci < nc; ci += 4) {          // 4 codes in parallel (16 lanes each)
      int k;
      if (doEx) k = ci + g16;
      else { const int sl = ci + g16; k = clist[w][sl < cnt ? sl : 0]; }  // dup harmless
      const float* erow = emb + (size_t)k * DDIM;
      double s = 0.0;
      #pragma unroll
      for (int qq = 0; qq < 4; ++qq) {
        const float4 ev = *(const float4*)(erow + qq * 64 + l16 * 4);     // coalesced
        const float4 zv = *(const float4*)(&zrow[w][qq * 64 + l16 * 4]);  // broadcast
        s += (double)zv.x * (double)ev.x + (double)zv.y * (double)ev.y
           + (double)zv.z * (double)ev.z + (double)zv.w * (double)ev.w;
      }
      #pragma unroll
      for (int o = 8; o; o >>= 1) s += __shfl_xor(s, o, 16);
      if (l16 == 0) {
        const float mm = (float)s;                   // exact dot -> one fp32 rounding
        const float d = (zzn + ee[k]) - 2.0f * mm;   // replicate ref quantization (d > 0)
        const unsigned long long c =
            ((unsigned long long)__float_as_uint(d) << 32) | (unsigned int)k;
        if (c < best) best = c;                      // lexicographic (d, k): first idx wins
      }
    }
    unsigned long long b0 = (l16 == 0) ? best : ~0ull;
    {
      const unsigned long long o1 = __shfl_xor(b0, 16, 64);
      b0 = o1 < b0 ? o1 : b0;
      const unsigned long long o2 = __shfl_xor(b0, 32, 64);
      b0 = o2 < b0 ? o2 : b0;
    }
    if (lane == 0) {
      const int k0 = (int)(b0 & 0xffffffffu);
      idx[n] = k0;
      out_idxf[n] = (float)k0;
      atomicAdd(&counts[k0], 1);
      dsum += (double)__uint_as_float((unsigned int)(b0 >> 32));  // winner d = sum((zq-z)^2)
    }
  }
  if (lane == 0) wsum[w] = dsum;
  __syncthreads();
  if (tid == 0) lsum[blockIdx.x] = wsum[0] + wsum[1] + wsum[2] + wsum[3];
}

// ---------------- scatter z_q: pure gather + coalesced NCHW write ----------------
__global__ __launch_bounds__(256) void k_scatter(
    const float* __restrict__ emb, const int* __restrict__ idx,
    float* __restrict__ out_zq) {
  __shared__ float et[64][257];   // 64 tokens x 256 dims, pad 257
  __shared__ int sidx[64];
  const int tg = blockIdx.x;      // 256 groups of 64 tokens
  const int n0 = tg * 64;
  const int b = n0 >> 10, hw0 = n0 & 1023;
  const int tid = threadIdx.x;
  if (tid < 64) sidx[tid] = idx[n0 + tid];
  __syncthreads();
  for (int i = tid; i < 16384; i += 256) {      // gather code rows (coalesced along d)
    const int t = i >> 8, d = i & 255;
    et[t][d] = emb[(size_t)sidx[t] * DDIM + d];
  }
  __syncthreads();
  float* ob = out_zq + (size_t)b * CHW + hw0;
  for (int i = tid; i < 16384; i += 256) {      // NCHW order: coalesced zq writes
    const int d = i >> 6, t = i & 63;
    ob[(size_t)d * HWD + t] = et[t][d];         // z_q_st == z_q numerically
  }
}

// ---------------- entropy + loss finals (single block) ----------------
__global__ __launch_bounds__(256) void k_histfinal(const int* __restrict__ counts,
                                                   const double* __restrict__ lsum,
                                                   float* __restrict__ out_loss,
                                                   float* __restrict__ out_perp) {
  __shared__ double w4[4], l4a[4];
  const int tid = threadIdx.x;
  double s = 0.0, l = 0.0;
  for (int i = tid; i < 16384; i += 256) {
    const float em = (float)counts[i] * (1.0f / 16384.0f);
    s += (double)(em * logf(em + 1e-10f));
  }
  for (int i = tid; i < 2048; i += 256) l += lsum[i];
  #pragma unroll
  for (int o = 32; o; o >>= 1) {
    s += __shfl_xor(s, o, 64);
    l += __shfl_xor(l, o, 64);
  }
  const int wid = tid >> 6, lane = tid & 63;
  if (lane == 0) { w4[wid] = s; l4a[wid] = l; }
  __syncthreads();
  if (tid == 0) {
    const double S = w4[0] + w4[1] + w4[2] + w4[3];
    const double L = l4a[0] + l4a[1] + l4a[2] + l4a[3];
    out_loss[0] = (float)(1.25 * L / 4194304.0);  // (1+BETA)*mean
    out_perp[0] = (float)exp(-S);
  }
}

extern "C" void kernel_launch(void* const* d_in, const int* in_sizes, int n_in,
                              void* d_out, int out_size, void* d_ws, size_t ws_size,
                              hipStream_t stream) {
  const float* z   = (const float*)d_in[0];   // [16,256,32,32]
  const float* emb = (const float*)d_in[1];   // [16384,256]
  float* out      = (float*)d_out;
  float* out_zq   = out;                      // 4194304
  float* out_loss = out + 4194304;
  float* out_perp = out + 4194305;
  float* out_idxf = out + 4194306;            // 16384 (idx as float)
  float* zt       = out;                      // [n][d] fp32; dead before k_scatter overwrites

  char* ws = (char*)d_ws;
  char* Ti8 = ws + WS_TI8;
  char* Ci8 = ws + WS_CI8;
  _Float16* M1 = (_Float16*)(ws + WS_M1);
  _Float16* M2 = (_Float16*)(ws + WS_M2);
  unsigned char* ARG = (unsigned char*)(ws + WS_ARG);
  unsigned char* flags = (unsigned char*)(ws + WS_FLG);
  float*  ee      = (float*)(ws + WS_EE);
  float*  zz      = (float*)(ws + WS_ZZ);
  int*    idx     = (int*)  (ws + WS_IDX);
  int*    counts  = (int*)  (ws + WS_CNT);
  double* lsum    = (double*)(ws + WS_LSUM);

  hipMemsetAsync(counts, 0, 65536, stream);

  k_prep <<<512, 256, 0, stream>>>(z, emb, Ti8, Ci8, zz, ee, zt, flags);
  k_mdist<<<2048, 256, 0, stream>>>(Ti8, Ci8, M1, M2, ARG);
  k_pick <<<2048, 256, 0, stream>>>(zt, emb, zz, ee, M1, M2, ARG, flags,
                                    idx, out_idxf, counts, lsum);
  k_scatter<<<256, 256, 0, stream>>>(emb, idx, out_zq);
  k_histfinal<<<1, 256, 0, stream>>>(counts, lsum, out_loss, out_perp);
}